// Round 5
// baseline (390.102 us; speedup 1.0000x reference)
//
#include <hip/hip_runtime.h>
#include <hip/hip_bf16.h>
#include <hip/hip_cooperative_groups.h>
#include <cstdint>
#include <type_traits>

namespace cg = cooperative_groups;

#define N_NODES 50000
#define N_EDGES 800000
#define D_IN 128
#define D_HID 256
#define D_OUT 128

#define MT1 782              // ceil(50000/64) m-tiles
#define EDGE_CHUNKS 12500    // N_EDGES / 64

typedef __bf16 bf16;
typedef __bf16 bf16x8 __attribute__((ext_vector_type(8)));
typedef __bf16 bf16x4 __attribute__((ext_vector_type(4)));
typedef float f32x4 __attribute__((ext_vector_type(4)));

// packed bf16 atomic add (2 channels per lane, 1 op) — validated round 4
__device__ __forceinline__ void flush_pk(bf16* __restrict__ agg, int node,
                                         int lane, float2 acc) {
  union { struct { bf16 x, y; } h; int i; } u;
  u.h.x = (bf16)acc.x; u.h.y = (bf16)acc.y;
  const bf16* p = &agg[(long)node * D_IN + lane * 2];
  asm volatile("global_atomic_pk_add_bf16 %0, %1, off"
               :: "v"(p), "v"(u.i) : "memory");
}

// ===========================================================================
// MEGA KERNEL (cooperative): prep | edge-agg | gemm1 | gemm2 with grid.sync()
// between phases. One dispatch = rocprof visibility + no kernel-drain gaps.
// LDS: 192*136 bf16 = 52.2 KB -> 3 blocks/CU (grid sized via occupancy query).
// Fragment layouts verified rounds 1-4:
//   A: a[j]=A[l15][quad*8+j]; B: b[j]=Wt[l15][quad*8+j]; C: row=quad*4+r, col=l15.
// ===========================================================================
__global__ __launch_bounds__(256) void mega_kernel(
    const float* __restrict__ x, const float* __restrict__ eps,
    const float* __restrict__ w1, const float* __restrict__ w2,
    const float* __restrict__ b1, const float* __restrict__ b2,
    const int* __restrict__ esrc, const int* __restrict__ edst,
    const float* __restrict__ evl,
    bf16* __restrict__ aggb, bf16* __restrict__ xb,
    bf16* __restrict__ w1t, bf16* __restrict__ w2t,
    bf16* __restrict__ h, float* __restrict__ out) {
  __shared__ alignas(16) bf16 smem[192 * 136];
  cg::grid_group grid = cg::this_grid();

  const int tid = threadIdx.x;
  const int gtid = blockIdx.x * 256 + tid;
  const int nthr = gridDim.x * 256;
  const int wave = tid >> 6;
  const int lane = tid & 63;
  const int l15 = lane & 15;
  const int quad = lane >> 4;

  // ---------------- phase 1: prep ----------------
  {
    const float scale = 1.0f + eps[0];
    for (int i = gtid; i < N_NODES * D_IN / 4; i += nthr) {
      float4 v = ((const float4*)x)[i];
      ((bf16x4*)xb)[i] = bf16x4{(bf16)v.x, (bf16)v.y, (bf16)v.z, (bf16)v.w};
      ((bf16x4*)aggb)[i] = bf16x4{(bf16)(v.x * scale), (bf16)(v.y * scale),
                                  (bf16)(v.z * scale), (bf16)(v.w * scale)};
    }
    for (int i = gtid; i < D_IN * D_HID; i += nthr) {
      int k = i >> 8, n = i & 255;          // w1[k][n]
      w1t[n * D_IN + k] = (bf16)w1[i];
    }
    for (int i = gtid; i < D_HID * D_OUT; i += nthr) {
      int k = i >> 7, n = i & 127;          // w2[k][n]
      w2t[n * D_HID + k] = (bf16)w2[i];
    }
  }
  grid.sync();

  // ---------------- phase 2: edge aggregation ----------------
  {
    const int waveId = (blockIdx.x << 2) | wave;
    const int totWaves = gridDim.x << 2;
    for (int c = waveId; c < EDGE_CHUNKS; c += totWaves) {
      const int e0 = __builtin_amdgcn_readfirstlane(c << 6);
      float2 acc = make_float2(0.f, 0.f);
      int cur = edst[e0];
      #pragma unroll 1
      for (int j = 0; j < 64; j += 16) {
        int s[16], d[16];
        float v[16];
        #pragma unroll
        for (int t = 0; t < 16; ++t) {
          s[t] = esrc[e0 + j + t];
          d[t] = edst[e0 + j + t];
          v[t] = evl[e0 + j + t];
        }
        int g[16];  // packed bf16x2
        #pragma unroll
        for (int t = 0; t < 16; ++t)
          g[t] = *(const int*)&xb[(long)s[t] * D_IN + lane * 2];
        #pragma unroll
        for (int t = 0; t < 16; ++t) {
          if (d[t] != cur) {  // wave-uniform flush at run boundary
            flush_pk(aggb, cur, lane, acc);
            acc.x = 0.f; acc.y = 0.f;
            cur = d[t];
          }
          float gx = __uint_as_float((unsigned)g[t] << 16);
          float gy = __uint_as_float((unsigned)g[t] & 0xffff0000u);
          acc.x = fmaf(v[t], gx, acc.x);
          acc.y = fmaf(v[t], gy, acc.y);
        }
      }
      flush_pk(aggb, cur, lane, acc);
    }
  }
  grid.sync();

  // ---------------- phase 3: h = relu(aggb @ w1t^T + b1) ----------------
  // 64x128 tiles (A re-read x2 instead of x4). As 64x136, Bs 128x136.
  {
    bf16* As = smem;
    bf16* Bs = smem + 64 * 136;
    for (int t = blockIdx.x; t < MT1 * 2; t += gridDim.x) {
      const int m0 = (t >> 1) * 64;
      const int n0 = (t & 1) * 128;
      #pragma unroll
      for (int it = 0; it < 4; ++it) {
        int idx = tid + it * 256;
        int r = idx >> 4, c8 = (idx & 15) << 3;
        int row = m0 + r; if (row >= N_NODES) row = N_NODES - 1;
        *(bf16x8*)&As[r * 136 + c8] = *(const bf16x8*)&aggb[(long)row * D_IN + c8];
      }
      #pragma unroll
      for (int it = 0; it < 8; ++it) {
        int idx = tid + it * 256;
        int r = idx >> 4, c8 = (idx & 15) << 3;
        *(bf16x8*)&Bs[r * 136 + c8] = *(const bf16x8*)&w1t[(long)(n0 + r) * D_IN + c8];
      }
      __syncthreads();
      const int wm = (wave & 1) * 32;
      const int wn = (wave >> 1) * 64;
      f32x4 acc[2][4] = {};
      #pragma unroll
      for (int ks = 0; ks < 4; ++ks) {
        int kq = ks * 32 + quad * 8;
        bf16x8 a0 = *(const bf16x8*)&As[(wm + l15) * 136 + kq];
        bf16x8 a1 = *(const bf16x8*)&As[(wm + 16 + l15) * 136 + kq];
        bf16x8 bf[4];
        #pragma unroll
        for (int nf = 0; nf < 4; ++nf)
          bf[nf] = *(const bf16x8*)&Bs[(wn + nf * 16 + l15) * 136 + kq];
        #pragma unroll
        for (int nf = 0; nf < 4; ++nf) {
          acc[0][nf] = __builtin_amdgcn_mfma_f32_16x16x32_bf16(a0, bf[nf], acc[0][nf], 0, 0, 0);
          acc[1][nf] = __builtin_amdgcn_mfma_f32_16x16x32_bf16(a1, bf[nf], acc[1][nf], 0, 0, 0);
        }
      }
      __syncthreads();
      #pragma unroll
      for (int nf = 0; nf < 4; ++nf) {
        int col = n0 + wn + nf * 16 + l15;
        float bv = b1[col];
        #pragma unroll
        for (int mf = 0; mf < 2; ++mf)
          #pragma unroll
          for (int r = 0; r < 4; ++r) {
            int row = m0 + wm + mf * 16 + quad * 4 + r;
            if (row < N_NODES)
              h[(long)row * D_HID + col] = (bf16)fmaxf(acc[mf][nf][r] + bv, 0.f);
          }
      }
    }
  }
  grid.sync();

  // ---------------- phase 4: out = h @ w2t^T + b2 ----------------
  // 64x64 tiles, K=256 in two 128-k stages.
  {
    bf16* As = smem;
    bf16* Bs = smem + 64 * 136;
    for (int t = blockIdx.x; t < MT1 * 2; t += gridDim.x) {
      const int m0 = (t >> 1) * 64;
      const int n0 = (t & 1) * 64;
      const int wm = (wave >> 1) * 32;
      const int wn = (wave & 1) * 32;
      f32x4 acc[2][2] = {};
      for (int kt = 0; kt < D_HID; kt += 128) {
        #pragma unroll
        for (int it = 0; it < 4; ++it) {
          int idx = tid + it * 256;
          int r = idx >> 4, c8 = (idx & 15) << 3;
          int row = m0 + r; if (row >= N_NODES) row = N_NODES - 1;
          *(bf16x8*)&As[r * 136 + c8] = *(const bf16x8*)&h[(long)row * D_HID + kt + c8];
        }
        #pragma unroll
        for (int it = 0; it < 4; ++it) {
          int idx = tid + it * 256;
          int r = idx >> 4, c8 = (idx & 15) << 3;
          *(bf16x8*)&Bs[r * 136 + c8] = *(const bf16x8*)&w2t[(long)(n0 + r) * D_HID + kt + c8];
        }
        __syncthreads();
        #pragma unroll
        for (int ks = 0; ks < 4; ++ks) {
          int kq = ks * 32 + quad * 8;
          bf16x8 a0 = *(const bf16x8*)&As[(wm + l15) * 136 + kq];
          bf16x8 a1 = *(const bf16x8*)&As[(wm + 16 + l15) * 136 + kq];
          bf16x8 b0 = *(const bf16x8*)&Bs[(wn + l15) * 136 + kq];
          bf16x8 b1f = *(const bf16x8*)&Bs[(wn + 16 + l15) * 136 + kq];
          acc[0][0] = __builtin_amdgcn_mfma_f32_16x16x32_bf16(a0, b0, acc[0][0], 0, 0, 0);
          acc[0][1] = __builtin_amdgcn_mfma_f32_16x16x32_bf16(a0, b1f, acc[0][1], 0, 0, 0);
          acc[1][0] = __builtin_amdgcn_mfma_f32_16x16x32_bf16(a1, b0, acc[1][0], 0, 0, 0);
          acc[1][1] = __builtin_amdgcn_mfma_f32_16x16x32_bf16(a1, b1f, acc[1][1], 0, 0, 0);
        }
        __syncthreads();
      }
      #pragma unroll
      for (int nf = 0; nf < 2; ++nf) {
        int col = n0 + wn + nf * 16 + l15;
        float bv = b2[col];
        #pragma unroll
        for (int mf = 0; mf < 2; ++mf)
          #pragma unroll
          for (int r = 0; r < 4; ++r) {
            int row = m0 + wm + mf * 16 + quad * 4 + r;
            if (row < N_NODES)
              out[(long)row * D_OUT + col] = acc[mf][nf][r] + bv;
          }
      }
    }
  }
}

// ===========================================================================
// Fallback path (round-4 kernels) in case cooperative launch/capture fails.
// ===========================================================================
__global__ __launch_bounds__(256) void prep_kernel(
    const float* __restrict__ x, const float* __restrict__ eps,
    const float* __restrict__ w1, const float* __restrict__ w2,
    bf16* __restrict__ aggb, bf16* __restrict__ xb,
    bf16* __restrict__ w1t, bf16* __restrict__ w2t) {
  const int i = blockIdx.x * 256 + threadIdx.x;
  const float scale = 1.0f + eps[0];
  float4 v = ((const float4*)x)[i];
  ((bf16x4*)xb)[i] = bf16x4{(bf16)v.x, (bf16)v.y, (bf16)v.z, (bf16)v.w};
  ((bf16x4*)aggb)[i] = bf16x4{(bf16)(v.x * scale), (bf16)(v.y * scale),
                              (bf16)(v.z * scale), (bf16)(v.w * scale)};
  if (i < D_IN * D_HID) {
    int k = i >> 8, n = i & 255;
    w1t[n * D_IN + k] = (bf16)w1[i];
  } else if (i < 2 * D_IN * D_HID) {
    int j = i - D_IN * D_HID;
    int k = j >> 7, n = j & 127;
    w2t[n * D_HID + k] = (bf16)w2[j];
  }
}

__global__ __launch_bounds__(256) void edge_agg_kernel(
    const bf16* __restrict__ xb, const int* __restrict__ src,
    const int* __restrict__ dst, const float* __restrict__ val,
    bf16* __restrict__ agg) {
  const int wave = (blockIdx.x << 2) | (threadIdx.x >> 6);
  const int lane = threadIdx.x & 63;
  const int e0 = __builtin_amdgcn_readfirstlane(wave << 6);
  float2 acc = make_float2(0.f, 0.f);
  int cur = dst[e0];
  #pragma unroll 1
  for (int j = 0; j < 64; j += 16) {
    int s[16], d[16];
    float v[16];
    #pragma unroll
    for (int t = 0; t < 16; ++t) {
      s[t] = src[e0 + j + t]; d[t] = dst[e0 + j + t]; v[t] = val[e0 + j + t];
    }
    int g[16];
    #pragma unroll
    for (int t = 0; t < 16; ++t)
      g[t] = *(const int*)&xb[(long)s[t] * D_IN + lane * 2];
    #pragma unroll
    for (int t = 0; t < 16; ++t) {
      if (d[t] != cur) {
        flush_pk(agg, cur, lane, acc);
        acc.x = 0.f; acc.y = 0.f;
        cur = d[t];
      }
      float gx = __uint_as_float((unsigned)g[t] << 16);
      float gy = __uint_as_float((unsigned)g[t] & 0xffff0000u);
      acc.x = fmaf(v[t], gx, acc.x);
      acc.y = fmaf(v[t], gy, acc.y);
    }
  }
  flush_pk(agg, cur, lane, acc);
}

template <int KDIM, int NOUT, bool RELU, typename TC>
__global__ __launch_bounds__(256) void gemm(
    const bf16* __restrict__ A, const bf16* __restrict__ Wt,
    const float* __restrict__ bias, TC* __restrict__ C) {
  constexpr int LDL = 136;
  __shared__ alignas(16) bf16 As[64][LDL];
  __shared__ alignas(16) bf16 Bs[64][LDL];
  const int tid = threadIdx.x;
  const int m0 = blockIdx.x * 64;
  const int n0 = blockIdx.y * 64;
  const int wave = tid >> 6;
  const int lane = tid & 63;
  const int wm = (wave >> 1) * 32;
  const int wn = (wave & 1) * 32;
  const int l15 = lane & 15;
  const int quad = lane >> 4;
  f32x4 acc[2][2] = {};
  for (int kt = 0; kt < KDIM; kt += 128) {
    #pragma unroll
    for (int it = 0; it < 4; ++it) {
      int idx = tid + it * 256;
      int r = idx >> 4, c8 = (idx & 15) << 3;
      int row = m0 + r; if (row >= N_NODES) row = N_NODES - 1;
      *(bf16x8*)&As[r][c8] = *(const bf16x8*)&A[(long)row * KDIM + kt + c8];
    }
    #pragma unroll
    for (int it = 0; it < 4; ++it) {
      int idx = tid + it * 256;
      int r = idx >> 4, c8 = (idx & 15) << 3;
      *(bf16x8*)&Bs[r][c8] = *(const bf16x8*)&Wt[(long)(n0 + r) * KDIM + kt + c8];
    }
    __syncthreads();
    #pragma unroll
    for (int ks = 0; ks < 4; ++ks) {
      int kq = ks * 32 + quad * 8;
      bf16x8 a0 = *(const bf16x8*)&As[wm + l15][kq];
      bf16x8 a1 = *(const bf16x8*)&As[wm + 16 + l15][kq];
      bf16x8 b0 = *(const bf16x8*)&Bs[wn + l15][kq];
      bf16x8 b1 = *(const bf16x8*)&Bs[wn + 16 + l15][kq];
      acc[0][0] = __builtin_amdgcn_mfma_f32_16x16x32_bf16(a0, b0, acc[0][0], 0, 0, 0);
      acc[0][1] = __builtin_amdgcn_mfma_f32_16x16x32_bf16(a0, b1, acc[0][1], 0, 0, 0);
      acc[1][0] = __builtin_amdgcn_mfma_f32_16x16x32_bf16(a1, b0, acc[1][0], 0, 0, 0);
      acc[1][1] = __builtin_amdgcn_mfma_f32_16x16x32_bf16(a1, b1, acc[1][1], 0, 0, 0);
    }
    __syncthreads();
  }
  #pragma unroll
  for (int mf = 0; mf < 2; ++mf)
    #pragma unroll
    for (int nf = 0; nf < 2; ++nf) {
      int col = n0 + wn + nf * 16 + l15;
      float bv = bias[col];
      #pragma unroll
      for (int r = 0; r < 4; ++r) {
        int row = m0 + wm + mf * 16 + quad * 4 + r;
        if (row < N_NODES) {
          float vv = acc[mf][nf][r] + bv;
          if constexpr (RELU) vv = fmaxf(vv, 0.f);
          if constexpr (std::is_same_v<TC, float>)
            C[(long)row * NOUT + col] = vv;
          else
            C[(long)row * NOUT + col] = (bf16)vv;
        }
      }
    }
}

// ---------------------------------------------------------------------------
extern "C" void kernel_launch(void* const* d_in, const int* in_sizes, int n_in,
                              void* d_out, int out_size, void* d_ws, size_t ws_size,
                              hipStream_t stream) {
  const float* x    = (const float*)d_in[0];
  const int*   esrc = (const int*)d_in[1];
  const int*   edst = (const int*)d_in[2];
  const float* evl  = (const float*)d_in[3];
  const float* eps  = (const float*)d_in[4];
  const float* w1   = (const float*)d_in[5];
  const float* b1   = (const float*)d_in[6];
  const float* w2   = (const float*)d_in[7];
  const float* b2   = (const float*)d_in[8];
  float* out = (float*)d_out;

  // workspace layout (16B aligned)
  bf16* aggb = (bf16*)d_ws;                       // 12.8 MB
  bf16* xb   = aggb + (size_t)N_NODES * D_IN;     // 12.8 MB
  bf16* h    = xb + (size_t)N_NODES * D_IN;       // 25.6 MB
  bf16* w1t  = h + (size_t)N_NODES * D_HID;       // 64 KB
  bf16* w2t  = w1t + D_IN * D_HID;                // 64 KB

  // cooperative grid: blocks/CU via occupancy query (LDS 52.2 KB -> 3/CU)
  int perCU = 0;
  hipError_t qerr = hipOccupancyMaxActiveBlocksPerMultiprocessor(
      &perCU, (const void*)mega_kernel, 256, 0);
  if (qerr != hipSuccess || perCU < 1) perCU = 1;
  int nblk = perCU * 256;  // 256 CUs on MI355X
  if (nblk > MT1 * 2) nblk = MT1 * 2;

  void* args[] = {(void*)&x, (void*)&eps, (void*)&w1, (void*)&w2,
                  (void*)&b1, (void*)&b2, (void*)&esrc, (void*)&edst,
                  (void*)&evl, (void*)&aggb, (void*)&xb, (void*)&w1t,
                  (void*)&w2t, (void*)&h, (void*)&out};
  hipError_t err = hipLaunchCooperativeKernel(
      (const void*)mega_kernel, dim3(nblk), dim3(256), args, 0, stream);

  if (err != hipSuccess) {
    // deterministic fallback: round-4 four-kernel path
    prep_kernel<<<(N_NODES * D_IN / 4) / 256, 256, 0, stream>>>(
        x, eps, w1, w2, aggb, xb, w1t, w2t);
    edge_agg_kernel<<<N_EDGES / 256, 256, 0, stream>>>(xb, esrc, edst, evl, aggb);
    gemm<D_IN, D_HID, true, bf16>
        <<<dim3((N_NODES + 63) / 64, D_HID / 64), 256, 0, stream>>>(aggb, w1t, b1, h);
    gemm<D_HID, D_OUT, false, float>
        <<<dim3((N_NODES + 63) / 64, D_OUT / 64), 256, 0, stream>>>(h, w2t, b2, out);
  }
}

// Round 6
// 247.741 us; speedup vs baseline: 1.5746x; 1.5746x over previous
//
#include <hip/hip_runtime.h>
#include <hip/hip_bf16.h>
#include <cstdint>
#include <type_traits>

#define N_NODES 50000
#define N_EDGES 800000
#define D_IN 128
#define D_HID 256
#define D_OUT 128
#define NODES_PER_WAVE 16   // 50000/16 = 3125 waves exactly

typedef __bf16 bf16;
typedef __bf16 bf16x8 __attribute__((ext_vector_type(8)));
typedef __bf16 bf16x4 __attribute__((ext_vector_type(4)));
typedef float f32x4 __attribute__((ext_vector_type(4)));

// ---------------------------------------------------------------------------
// Kernel 1: xb = bf16(x) for the edge gather + transposed bf16 weights.
// (agg is now produced directly by the edge kernel — no pre-init needed.)
// grid: 6250 x 256 = N*D_IN/4 exactly.
// ---------------------------------------------------------------------------
__global__ __launch_bounds__(256) void prep_kernel(
    const float* __restrict__ x, const float* __restrict__ w1,
    const float* __restrict__ w2, bf16* __restrict__ xb,
    bf16* __restrict__ w1t, bf16* __restrict__ w2t) {
  const int i = blockIdx.x * 256 + threadIdx.x;
  float4 v = ((const float4*)x)[i];
  ((bf16x4*)xb)[i] = bf16x4{(bf16)v.x, (bf16)v.y, (bf16)v.z, (bf16)v.w};
  if (i < D_IN * D_HID) {            // 32768
    int k = i >> 8, n = i & 255;     // w1[k][n]
    w1t[n * D_IN + k] = (bf16)w1[i];
  } else if (i < 2 * D_IN * D_HID) { // next 32768
    int j = i - D_IN * D_HID;
    int k = j >> 7, n = j & 127;     // w2[k][n]
    w2t[n * D_HID + k] = (bf16)w2[j];
  }
}

// ---------------------------------------------------------------------------
// Kernel 2: node-centric CSR-style aggregation over the SORTED edge list.
// Wave w owns nodes [16w, 16w+16): binary-search (uniform) the first edge,
// then scan edges with the 16-deep gather pipeline. Each agg row = fp32
// register accumulation of self-term + all its edges, written ONCE as bf16.
// NO atomics (round 5 lesson: R1-R4 atomic versions churned ~62 MB of HBM
// writes; node ownership is exclusive by construction).
// grid: 782 x 256 (4 waves/block) -> 3128 waves >= 3125 needed.
// ---------------------------------------------------------------------------
__device__ __forceinline__ void store_row(bf16* __restrict__ agg, int node,
                                          int lane, float2 a) {
  union { struct { bf16 x, y; } h; int i; } u;
  u.h.x = (bf16)a.x; u.h.y = (bf16)a.y;
  *(int*)&agg[(long)node * D_IN + lane * 2] = u.i;
}

__global__ __launch_bounds__(256) void edge_csr_kernel(
    const float* __restrict__ x, const bf16* __restrict__ xb,
    const int* __restrict__ esrc, const int* __restrict__ edst,
    const float* __restrict__ evl, const float* __restrict__ eps,
    bf16* __restrict__ agg) {
  const int w = (blockIdx.x << 2) | (threadIdx.x >> 6);
  const int lane = threadIdx.x & 63;
  const int n_begin = w * NODES_PER_WAVE;
  if (n_begin >= N_NODES) return;
  const int n_end = n_begin + NODES_PER_WAVE;  // 50000 % 16 == 0
  const float scale = 1.0f + eps[0];
  const float2* x2 = (const float2*)x;

  // prefetch the 16 self-terms (independent loads, hides node-switch latency)
  float2 self[NODES_PER_WAVE];
  #pragma unroll
  for (int n = 0; n < NODES_PER_WAVE; ++n) {
    float2 q = x2[(long)(n_begin + n) * 64 + lane];
    self[n] = make_float2(scale * q.x, scale * q.y);
  }

  // uniform lower_bound(edst, n_begin)
  int lo = 0, hi = N_EDGES;
  while (lo < hi) {
    int mid = (lo + hi) >> 1;
    if (edst[mid] < n_begin) lo = mid + 1; else hi = mid;
  }
  int e = __builtin_amdgcn_readfirstlane(lo);

  int cur = n_begin;
  float2 acc = self[0];
  bool done = false;

  #pragma unroll 1
  while (!done) {
    int s[16], d[16];
    float v[16];
    #pragma unroll
    for (int t = 0; t < 16; ++t) {
      int et = e + t;
      bool ok = et < N_EDGES;
      s[t] = ok ? esrc[et] : 0;
      d[t] = ok ? edst[et] : N_NODES;  // sentinel terminates
      v[t] = ok ? evl[et] : 0.f;
    }
    int g[16];  // packed bf16x2 gathers, 16 in flight
    #pragma unroll
    for (int t = 0; t < 16; ++t)
      g[t] = *(const int*)&xb[(long)s[t] * D_IN + lane * 2];
    #pragma unroll
    for (int t = 0; t < 16; ++t) {
      if (!done) {
        if (d[t] != cur) {               // wave-uniform branch (d is sorted)
          if (d[t] >= n_end) {
            done = true;                 // remaining edges belong to next wave
          } else {
            store_row(agg, cur, lane, acc);
            for (int n = cur + 1; n < d[t]; ++n)   // empty nodes (~never)
              store_row(agg, n, lane, self[n - n_begin]);
            cur = d[t];
            acc = self[cur - n_begin];
          }
        }
        if (!done) {
          float gx = __uint_as_float((unsigned)g[t] << 16);
          float gy = __uint_as_float((unsigned)g[t] & 0xffff0000u);
          acc.x = fmaf(v[t], gx, acc.x);
          acc.y = fmaf(v[t], gy, acc.y);
        }
      }
    }
    e += 16;
  }
  store_row(agg, cur, lane, acc);
  for (int n = cur + 1; n < n_end; ++n)
    store_row(agg, n, lane, self[n - n_begin]);
}

// ---------------------------------------------------------------------------
// Kernels 3/4: C[M,NOUT] = act(A[M,KDIM] @ Wt[NOUT,KDIM]^T + bias).
// Verbatim from round 4 (passed, ~15-17 us each est.). LDS-staged 64x64
// tiles, stride 136 (2-way bank aliasing only). Fragment layouts verified
// rounds 1-4: A: a[j]=A[l15][quad*8+j]; B: b[j]=Wt[l15][quad*8+j];
// C: row=quad*4+r, col=l15.
// ---------------------------------------------------------------------------
template <int KDIM, int NOUT, bool RELU, typename TC>
__global__ __launch_bounds__(256) void gemm(
    const bf16* __restrict__ A, const bf16* __restrict__ Wt,
    const float* __restrict__ bias, TC* __restrict__ C) {
  constexpr int LDL = 136;
  __shared__ alignas(16) bf16 As[64][LDL];
  __shared__ alignas(16) bf16 Bs[64][LDL];
  const int tid = threadIdx.x;
  const int m0 = blockIdx.x * 64;
  const int n0 = blockIdx.y * 64;
  const int wave = tid >> 6;
  const int lane = tid & 63;
  const int wm = (wave >> 1) * 32;
  const int wn = (wave & 1) * 32;
  const int l15 = lane & 15;
  const int quad = lane >> 4;
  f32x4 acc[2][2] = {};
  for (int kt = 0; kt < KDIM; kt += 128) {
    #pragma unroll
    for (int it = 0; it < 4; ++it) {
      int idx = tid + it * 256;
      int r = idx >> 4, c8 = (idx & 15) << 3;
      int row = m0 + r; if (row >= N_NODES) row = N_NODES - 1;
      *(bf16x8*)&As[r][c8] = *(const bf16x8*)&A[(long)row * KDIM + kt + c8];
    }
    #pragma unroll
    for (int it = 0; it < 4; ++it) {
      int idx = tid + it * 256;
      int r = idx >> 4, c8 = (idx & 15) << 3;
      *(bf16x8*)&Bs[r][c8] = *(const bf16x8*)&Wt[(long)(n0 + r) * KDIM + kt + c8];
    }
    __syncthreads();
    #pragma unroll
    for (int ks = 0; ks < 4; ++ks) {
      int kq = ks * 32 + quad * 8;
      bf16x8 a0 = *(const bf16x8*)&As[wm + l15][kq];
      bf16x8 a1 = *(const bf16x8*)&As[wm + 16 + l15][kq];
      bf16x8 b0 = *(const bf16x8*)&Bs[wn + l15][kq];
      bf16x8 b1 = *(const bf16x8*)&Bs[wn + 16 + l15][kq];
      acc[0][0] = __builtin_amdgcn_mfma_f32_16x16x32_bf16(a0, b0, acc[0][0], 0, 0, 0);
      acc[0][1] = __builtin_amdgcn_mfma_f32_16x16x32_bf16(a0, b1, acc[0][1], 0, 0, 0);
      acc[1][0] = __builtin_amdgcn_mfma_f32_16x16x32_bf16(a1, b0, acc[1][0], 0, 0, 0);
      acc[1][1] = __builtin_amdgcn_mfma_f32_16x16x32_bf16(a1, b1, acc[1][1], 0, 0, 0);
    }
    __syncthreads();
  }
  #pragma unroll
  for (int mf = 0; mf < 2; ++mf)
    #pragma unroll
    for (int nf = 0; nf < 2; ++nf) {
      int col = n0 + wn + nf * 16 + l15;
      float bv = bias[col];
      #pragma unroll
      for (int r = 0; r < 4; ++r) {
        int row = m0 + wm + mf * 16 + quad * 4 + r;
        if (row < N_NODES) {
          float vv = acc[mf][nf][r] + bv;
          if constexpr (RELU) vv = fmaxf(vv, 0.f);
          if constexpr (std::is_same_v<TC, float>)
            C[(long)row * NOUT + col] = vv;
          else
            C[(long)row * NOUT + col] = (bf16)vv;
        }
      }
    }
}

// ---------------------------------------------------------------------------
extern "C" void kernel_launch(void* const* d_in, const int* in_sizes, int n_in,
                              void* d_out, int out_size, void* d_ws, size_t ws_size,
                              hipStream_t stream) {
  const float* x    = (const float*)d_in[0];
  const int*   esrc = (const int*)d_in[1];
  const int*   edst = (const int*)d_in[2];
  const float* evl  = (const float*)d_in[3];
  const float* eps  = (const float*)d_in[4];
  const float* w1   = (const float*)d_in[5];
  const float* b1   = (const float*)d_in[6];
  const float* w2   = (const float*)d_in[7];
  const float* b2   = (const float*)d_in[8];
  float* out = (float*)d_out;

  // workspace layout (16B aligned)
  bf16* agg = (bf16*)d_ws;                        // 12.8 MB
  bf16* xb  = agg + (size_t)N_NODES * D_IN;       // 12.8 MB
  bf16* h   = xb + (size_t)N_NODES * D_IN;        // 25.6 MB
  bf16* w1t = h + (size_t)N_NODES * D_HID;        // 64 KB
  bf16* w2t = w1t + D_IN * D_HID;                 // 64 KB

  prep_kernel<<<(N_NODES * D_IN / 4) / 256, 256, 0, stream>>>(
      x, w1, w2, xb, w1t, w2t);
  edge_csr_kernel<<<(N_NODES / NODES_PER_WAVE + 3) / 4, 256, 0, stream>>>(
      x, xb, esrc, edst, evl, eps, agg);
  gemm<D_IN, D_HID, true, bf16>
      <<<dim3((N_NODES + 63) / 64, D_HID / 64), 256, 0, stream>>>(agg, w1t, b1, h);
  gemm<D_HID, D_OUT, false, float>
      <<<dim3((N_NODES + 63) / 64, D_OUT / 64), 256, 0, stream>>>(h, w2t, b2, out);
}

// Round 7
// 245.260 us; speedup vs baseline: 1.5906x; 1.0101x over previous
//
#include <hip/hip_runtime.h>
#include <hip/hip_bf16.h>
#include <cstdint>
#include <type_traits>

#define N_NODES 50000
#define N_EDGES 800000
#define D_IN 128
#define D_HID 256
#define D_OUT 128
#define NPW 4   // nodes per wave: 50000/4 = 12500 waves (R4-level parallelism)

typedef __bf16 bf16;
typedef __bf16 bf16x8 __attribute__((ext_vector_type(8)));
typedef __bf16 bf16x4 __attribute__((ext_vector_type(4)));
typedef float f32x4 __attribute__((ext_vector_type(4)));

// ---------------------------------------------------------------------------
// Kernel 1: xb = bf16(x) for the edge gather + transposed bf16 weights.
// grid: 6250 x 256 = N*D_IN/4 exactly.
// ---------------------------------------------------------------------------
__global__ __launch_bounds__(256) void prep_kernel(
    const float* __restrict__ x, const float* __restrict__ w1,
    const float* __restrict__ w2, bf16* __restrict__ xb,
    bf16* __restrict__ w1t, bf16* __restrict__ w2t) {
  const int i = blockIdx.x * 256 + threadIdx.x;
  float4 v = ((const float4*)x)[i];
  ((bf16x4*)xb)[i] = bf16x4{(bf16)v.x, (bf16)v.y, (bf16)v.z, (bf16)v.w};
  if (i < D_IN * D_HID) {            // 32768
    int k = i >> 8, n = i & 255;     // w1[k][n]
    w1t[n * D_IN + k] = (bf16)w1[i];
  } else if (i < 2 * D_IN * D_HID) { // next 32768
    int j = i - D_IN * D_HID;
    int k = j >> 7, n = j & 127;     // w2[k][n]
    w2t[n * D_HID + k] = (bf16)w2[j];
  }
}

// ---------------------------------------------------------------------------
// Kernel 2: node-centric aggregation over the SORTED edge list, NO atomics.
// Round-6 lesson: 16 nodes/wave gave only 3128 waves -> latency-bound at 13%
// occupancy (145 us). Now 4 nodes/wave -> 12500 waves (R4 parallelism) with
// the same exclusive-ownership single-write structure:
//   wave w owns nodes [4w, 4w+4): uniform binary-search of the first edge,
//   16-deep batched gather pipeline, fp32 register accumulation, each agg
//   row written ONCE as packed bf16.
// Self-terms read from xb (bf16): saves the 25.6 MB fp32 x re-read; with the
// final bf16 store this is a <=1-ulp double-round (exact when eps==0).
// grid: 3125 x 256 (4 waves/block) = 12500 waves exactly.
// ---------------------------------------------------------------------------
__device__ __forceinline__ void store_row(bf16* __restrict__ agg, int node,
                                          int lane, float2 a) {
  union { struct { bf16 x, y; } h; int i; } u;
  u.h.x = (bf16)a.x; u.h.y = (bf16)a.y;
  *(int*)&agg[(long)node * D_IN + lane * 2] = u.i;
}

__global__ __launch_bounds__(256) void edge_csr_kernel(
    const bf16* __restrict__ xb, const int* __restrict__ esrc,
    const int* __restrict__ edst, const float* __restrict__ evl,
    const float* __restrict__ eps, bf16* __restrict__ agg) {
  const int w = (blockIdx.x << 2) | (threadIdx.x >> 6);
  const int lane = threadIdx.x & 63;
  const int n_begin = w * NPW;
  if (n_begin >= N_NODES) return;
  const int n_end = n_begin + NPW;  // 50000 % 4 == 0
  const float scale = 1.0f + eps[0];

  // self-terms for the 4 owned nodes (independent loads)
  float2 self[NPW];
  #pragma unroll
  for (int n = 0; n < NPW; ++n) {
    int p = *(const int*)&xb[(long)(n_begin + n) * D_IN + lane * 2];
    float sx = __uint_as_float((unsigned)p << 16);
    float sy = __uint_as_float((unsigned)p & 0xffff0000u);
    self[n] = make_float2(scale * sx, scale * sy);
  }

  // uniform lower_bound(edst, n_begin)
  int lo = 0, hi = N_EDGES;
  while (lo < hi) {
    int mid = (lo + hi) >> 1;
    if (edst[mid] < n_begin) lo = mid + 1; else hi = mid;
  }
  int e = __builtin_amdgcn_readfirstlane(lo);

  int cur = n_begin;
  float2 acc = self[0];
  bool done = false;

  #pragma unroll 1
  while (!done) {
    int s[16], d[16];
    float v[16];
    #pragma unroll
    for (int t = 0; t < 16; ++t) {
      int et = e + t;
      bool ok = et < N_EDGES;
      s[t] = ok ? esrc[et] : 0;
      d[t] = ok ? edst[et] : N_NODES;  // sentinel terminates
      v[t] = ok ? evl[et] : 0.f;
    }
    int g[16];  // packed bf16x2 gathers, 16 in flight
    #pragma unroll
    for (int t = 0; t < 16; ++t)
      g[t] = *(const int*)&xb[(long)s[t] * D_IN + lane * 2];
    #pragma unroll
    for (int t = 0; t < 16; ++t) {
      if (!done) {
        if (d[t] != cur) {               // wave-uniform (d sorted)
          if (d[t] >= n_end) {
            done = true;                 // rest belongs to later waves
          } else {
            store_row(agg, cur, lane, acc);
            for (int n = cur + 1; n < d[t]; ++n)   // empty nodes (~never)
              store_row(agg, n, lane, self[n - n_begin]);
            cur = d[t];
            acc = self[cur - n_begin];
          }
        }
        if (!done) {
          float gx = __uint_as_float((unsigned)g[t] << 16);
          float gy = __uint_as_float((unsigned)g[t] & 0xffff0000u);
          acc.x = fmaf(v[t], gx, acc.x);
          acc.y = fmaf(v[t], gy, acc.y);
        }
      }
    }
    e += 16;
  }
  store_row(agg, cur, lane, acc);
  for (int n = cur + 1; n < n_end; ++n)
    store_row(agg, n, lane, self[n - n_begin]);
}

// ---------------------------------------------------------------------------
// Kernels 3/4: C[M,NOUT] = act(A[M,KDIM] @ Wt[NOUT,KDIM]^T + bias).
// Verbatim from rounds 4/6. LDS-staged 64x64 tiles, stride 136 (2-way bank
// aliasing only). Fragment layouts verified rounds 1-6:
//   A: a[j]=A[l15][quad*8+j]; B: b[j]=Wt[l15][quad*8+j]; C: row=quad*4+r, col=l15.
// ---------------------------------------------------------------------------
template <int KDIM, int NOUT, bool RELU, typename TC>
__global__ __launch_bounds__(256) void gemm(
    const bf16* __restrict__ A, const bf16* __restrict__ Wt,
    const float* __restrict__ bias, TC* __restrict__ C) {
  constexpr int LDL = 136;
  __shared__ alignas(16) bf16 As[64][LDL];
  __shared__ alignas(16) bf16 Bs[64][LDL];
  const int tid = threadIdx.x;
  const int m0 = blockIdx.x * 64;
  const int n0 = blockIdx.y * 64;
  const int wave = tid >> 6;
  const int lane = tid & 63;
  const int wm = (wave >> 1) * 32;
  const int wn = (wave & 1) * 32;
  const int l15 = lane & 15;
  const int quad = lane >> 4;
  f32x4 acc[2][2] = {};
  for (int kt = 0; kt < KDIM; kt += 128) {
    #pragma unroll
    for (int it = 0; it < 4; ++it) {
      int idx = tid + it * 256;
      int r = idx >> 4, c8 = (idx & 15) << 3;
      int row = m0 + r; if (row >= N_NODES) row = N_NODES - 1;
      *(bf16x8*)&As[r][c8] = *(const bf16x8*)&A[(long)row * KDIM + kt + c8];
    }
    #pragma unroll
    for (int it = 0; it < 4; ++it) {
      int idx = tid + it * 256;
      int r = idx >> 4, c8 = (idx & 15) << 3;
      *(bf16x8*)&Bs[r][c8] = *(const bf16x8*)&Wt[(long)(n0 + r) * KDIM + kt + c8];
    }
    __syncthreads();
    #pragma unroll
    for (int ks = 0; ks < 4; ++ks) {
      int kq = ks * 32 + quad * 8;
      bf16x8 a0 = *(const bf16x8*)&As[wm + l15][kq];
      bf16x8 a1 = *(const bf16x8*)&As[wm + 16 + l15][kq];
      bf16x8 b0 = *(const bf16x8*)&Bs[wn + l15][kq];
      bf16x8 b1 = *(const bf16x8*)&Bs[wn + 16 + l15][kq];
      acc[0][0] = __builtin_amdgcn_mfma_f32_16x16x32_bf16(a0, b0, acc[0][0], 0, 0, 0);
      acc[0][1] = __builtin_amdgcn_mfma_f32_16x16x32_bf16(a0, b1, acc[0][1], 0, 0, 0);
      acc[1][0] = __builtin_amdgcn_mfma_f32_16x16x32_bf16(a1, b0, acc[1][0], 0, 0, 0);
      acc[1][1] = __builtin_amdgcn_mfma_f32_16x16x32_bf16(a1, b1, acc[1][1], 0, 0, 0);
    }
    __syncthreads();
  }
  #pragma unroll
  for (int mf = 0; mf < 2; ++mf)
    #pragma unroll
    for (int nf = 0; nf < 2; ++nf) {
      int col = n0 + wn + nf * 16 + l15;
      float bv = bias[col];
      #pragma unroll
      for (int r = 0; r < 4; ++r) {
        int row = m0 + wm + mf * 16 + quad * 4 + r;
        if (row < N_NODES) {
          float vv = acc[mf][nf][r] + bv;
          if constexpr (RELU) vv = fmaxf(vv, 0.f);
          if constexpr (std::is_same_v<TC, float>)
            C[(long)row * NOUT + col] = vv;
          else
            C[(long)row * NOUT + col] = (bf16)vv;
        }
      }
    }
}

// ---------------------------------------------------------------------------
extern "C" void kernel_launch(void* const* d_in, const int* in_sizes, int n_in,
                              void* d_out, int out_size, void* d_ws, size_t ws_size,
                              hipStream_t stream) {
  const float* x    = (const float*)d_in[0];
  const int*   esrc = (const int*)d_in[1];
  const int*   edst = (const int*)d_in[2];
  const float* evl  = (const float*)d_in[3];
  const float* eps  = (const float*)d_in[4];
  const float* w1   = (const float*)d_in[5];
  const float* b1   = (const float*)d_in[6];
  const float* w2   = (const float*)d_in[7];
  const float* b2   = (const float*)d_in[8];
  float* out = (float*)d_out;

  // workspace layout (16B aligned)
  bf16* agg = (bf16*)d_ws;                        // 12.8 MB
  bf16* xb  = agg + (size_t)N_NODES * D_IN;       // 12.8 MB
  bf16* h   = xb + (size_t)N_NODES * D_IN;        // 25.6 MB
  bf16* w1t = h + (size_t)N_NODES * D_HID;        // 64 KB
  bf16* w2t = w1t + D_IN * D_HID;                 // 64 KB

  prep_kernel<<<(N_NODES * D_IN / 4) / 256, 256, 0, stream>>>(
      x, w1, w2, xb, w1t, w2t);
  edge_csr_kernel<<<(N_NODES / NPW + 3) / 4, 256, 0, stream>>>(
      xb, esrc, edst, evl, eps, agg);
  gemm<D_IN, D_HID, true, bf16>
      <<<dim3((N_NODES + 63) / 64, D_HID / 64), 256, 0, stream>>>(agg, w1t, b1, h);
  gemm<D_HID, D_OUT, false, float>
      <<<dim3((N_NODES + 63) / 64, D_OUT / 64), 256, 0, stream>>>(h, w2t, b2, out);
}

// Round 8
// 212.215 us; speedup vs baseline: 1.8382x; 1.1557x over previous
//
#include <hip/hip_runtime.h>
#include <hip/hip_bf16.h>
#include <cstdint>
#include <type_traits>

#define N_NODES 50000
#define N_EDGES 800000
#define D_IN 128
#define D_HID 256
#define D_OUT 128
#define NPW 4   // nodes per wave: 50000/4 = 12500 waves

typedef __bf16 bf16;
typedef __bf16 bf16x8 __attribute__((ext_vector_type(8)));
typedef __bf16 bf16x4 __attribute__((ext_vector_type(4)));
typedef float f32x4 __attribute__((ext_vector_type(4)));

// ---------------------------------------------------------------------------
// Kernel 1: xb = bf16(x) for the edge gather + transposed bf16 weights.
// grid: 6250 x 256 = N*D_IN/4 exactly.
// ---------------------------------------------------------------------------
__global__ __launch_bounds__(256) void prep_kernel(
    const float* __restrict__ x, const float* __restrict__ w1,
    const float* __restrict__ w2, bf16* __restrict__ xb,
    bf16* __restrict__ w1t, bf16* __restrict__ w2t) {
  const int i = blockIdx.x * 256 + threadIdx.x;
  float4 v = ((const float4*)x)[i];
  ((bf16x4*)xb)[i] = bf16x4{(bf16)v.x, (bf16)v.y, (bf16)v.z, (bf16)v.w};
  if (i < D_IN * D_HID) {            // 32768
    int k = i >> 8, n = i & 255;     // w1[k][n]
    w1t[n * D_IN + k] = (bf16)w1[i];
  } else if (i < 2 * D_IN * D_HID) { // next 32768
    int j = i - D_IN * D_HID;
    int k = j >> 7, n = j & 127;     // w2[k][n]
    w2t[n * D_HID + k] = (bf16)w2[j];
  }
}

// ---------------------------------------------------------------------------
// Kernel 2: node-centric aggregation over the SORTED edge list, NO atomics.
// ROUND-7 COUNTER EVIDENCE: LDS_Block_Size=8192 + 425k bank conflicts +
// VGPR=28 in a no-__shared__ kernel => PromoteAlloca demoted the staging
// arrays to LDS (SROA defeated by the `done` flag); the 16-deep gather
// pipeline never existed. Fix:
//  (a) no flags: [e_begin, e_end) from TWO independent uniform binary
//      searches; trailing lanes clamp to ee-1 with v=0 (preserves run
//      structure, zero contribution) -> simple PHIs, SROA succeeds.
//  (b) __builtin_amdgcn_sched_barrier(0) after issuing the 16 gathers:
//      forbids sinking loads into the serial consume chain -> real MLP.
// grid: 3125 x 256 (4 waves/block) = 12500 waves exactly.
// ---------------------------------------------------------------------------
__device__ __forceinline__ void store_row(bf16* __restrict__ agg, int node,
                                          int lane, float2 a) {
  union { struct { bf16 x, y; } h; int i; } u;
  u.h.x = (bf16)a.x; u.h.y = (bf16)a.y;
  *(int*)&agg[(long)node * D_IN + lane * 2] = u.i;
}

__global__ __launch_bounds__(256) void edge_csr_kernel(
    const bf16* __restrict__ xb, const int* __restrict__ esrc,
    const int* __restrict__ edst, const float* __restrict__ evl,
    const float* __restrict__ eps, bf16* __restrict__ agg) {
  const int w = (blockIdx.x << 2) | (threadIdx.x >> 6);
  const int lane = threadIdx.x & 63;
  const int n_begin = w * NPW;
  if (n_begin >= N_NODES) return;
  const int n_end = n_begin + NPW;  // 50000 % 4 == 0
  const float scale = 1.0f + eps[0];

  // self-terms for the 4 owned nodes (independent loads)
  float2 self[NPW];
  #pragma unroll
  for (int n = 0; n < NPW; ++n) {
    int p = *(const int*)&xb[(long)(n_begin + n) * D_IN + lane * 2];
    float sx = __uint_as_float((unsigned)p << 16);
    float sy = __uint_as_float((unsigned)p & 0xffff0000u);
    self[n] = make_float2(scale * sx, scale * sy);
  }

  // two independent uniform binary searches (chains overlap each other)
  int lo0 = 0, hi0 = N_EDGES, lo1 = 0, hi1 = N_EDGES;
  #pragma unroll 1
  while (lo0 < hi0 || lo1 < hi1) {
    if (lo0 < hi0) {
      int mid = (lo0 + hi0) >> 1;
      if (edst[mid] < n_begin) lo0 = mid + 1; else hi0 = mid;
    }
    if (lo1 < hi1) {
      int mid = (lo1 + hi1) >> 1;
      if (edst[mid] < n_end) lo1 = mid + 1; else hi1 = mid;
    }
  }
  const int eb = __builtin_amdgcn_readfirstlane(lo0);
  const int ee = __builtin_amdgcn_readfirstlane(lo1);

  int cur = n_begin;
  float2 acc = self[0];

  #pragma unroll 1
  for (int e = eb; e < ee; e += 16) {
    int s[16], d[16];
    float v[16];
    #pragma unroll
    for (int t = 0; t < 16; ++t) {
      int et = e + t;
      bool act = et < ee;
      if (!act) et = ee - 1;          // replicate last edge with v=0
      s[t] = esrc[et];
      d[t] = edst[et];
      v[t] = act ? evl[et] : 0.f;
    }
    int g[16];  // packed bf16x2 gathers — 16 independent loads in flight
    #pragma unroll
    for (int t = 0; t < 16; ++t)
      g[t] = *(const int*)&xb[(long)s[t] * D_IN + lane * 2];
    __builtin_amdgcn_sched_barrier(0);  // pin: all gathers issued before use
    #pragma unroll
    for (int t = 0; t < 16; ++t) {
      if (d[t] != cur) {               // wave-uniform (d sorted, in range)
        store_row(agg, cur, lane, acc);
        for (int n = cur + 1; n < d[t]; ++n)   // empty-node gap (~never)
          store_row(agg, n, lane, self[n - n_begin]);
        cur = d[t];
        acc = self[cur - n_begin];
      }
      float gx = __uint_as_float((unsigned)g[t] << 16);
      float gy = __uint_as_float((unsigned)g[t] & 0xffff0000u);
      acc.x = fmaf(v[t], gx, acc.x);
      acc.y = fmaf(v[t], gy, acc.y);
    }
  }
  store_row(agg, cur, lane, acc);
  for (int n = cur + 1; n < n_end; ++n)
    store_row(agg, n, lane, self[n - n_begin]);
}

// ---------------------------------------------------------------------------
// Kernels 3/4: C[M,NOUT] = act(A[M,KDIM] @ Wt[NOUT,KDIM]^T + bias).
// Verbatim from rounds 4/6/7. Fragment layouts verified rounds 1-7:
//   A: a[j]=A[l15][quad*8+j]; B: b[j]=Wt[l15][quad*8+j]; C: row=quad*4+r, col=l15.
// ---------------------------------------------------------------------------
template <int KDIM, int NOUT, bool RELU, typename TC>
__global__ __launch_bounds__(256) void gemm(
    const bf16* __restrict__ A, const bf16* __restrict__ Wt,
    const float* __restrict__ bias, TC* __restrict__ C) {
  constexpr int LDL = 136;
  __shared__ alignas(16) bf16 As[64][LDL];
  __shared__ alignas(16) bf16 Bs[64][LDL];
  const int tid = threadIdx.x;
  const int m0 = blockIdx.x * 64;
  const int n0 = blockIdx.y * 64;
  const int wave = tid >> 6;
  const int lane = tid & 63;
  const int wm = (wave >> 1) * 32;
  const int wn = (wave & 1) * 32;
  const int l15 = lane & 15;
  const int quad = lane >> 4;
  f32x4 acc[2][2] = {};
  for (int kt = 0; kt < KDIM; kt += 128) {
    #pragma unroll
    for (int it = 0; it < 4; ++it) {
      int idx = tid + it * 256;
      int r = idx >> 4, c8 = (idx & 15) << 3;
      int row = m0 + r; if (row >= N_NODES) row = N_NODES - 1;
      *(bf16x8*)&As[r][c8] = *(const bf16x8*)&A[(long)row * KDIM + kt + c8];
    }
    #pragma unroll
    for (int it = 0; it < 4; ++it) {
      int idx = tid + it * 256;
      int r = idx >> 4, c8 = (idx & 15) << 3;
      *(bf16x8*)&Bs[r][c8] = *(const bf16x8*)&Wt[(long)(n0 + r) * KDIM + kt + c8];
    }
    __syncthreads();
    #pragma unroll
    for (int ks = 0; ks < 4; ++ks) {
      int kq = ks * 32 + quad * 8;
      bf16x8 a0 = *(const bf16x8*)&As[wm + l15][kq];
      bf16x8 a1 = *(const bf16x8*)&As[wm + 16 + l15][kq];
      bf16x8 b0 = *(const bf16x8*)&Bs[wn + l15][kq];
      bf16x8 b1 = *(const bf16x8*)&Bs[wn + 16 + l15][kq];
      acc[0][0] = __builtin_amdgcn_mfma_f32_16x16x32_bf16(a0, b0, acc[0][0], 0, 0, 0);
      acc[0][1] = __builtin_amdgcn_mfma_f32_16x16x32_bf16(a0, b1, acc[0][1], 0, 0, 0);
      acc[1][0] = __builtin_amdgcn_mfma_f32_16x16x32_bf16(a1, b0, acc[1][0], 0, 0, 0);
      acc[1][1] = __builtin_amdgcn_mfma_f32_16x16x32_bf16(a1, b1, acc[1][1], 0, 0, 0);
    }
    __syncthreads();
  }
  #pragma unroll
  for (int mf = 0; mf < 2; ++mf)
    #pragma unroll
    for (int nf = 0; nf < 2; ++nf) {
      int col = n0 + wn + nf * 16 + l15;
      float bv = bias[col];
      #pragma unroll
      for (int r = 0; r < 4; ++r) {
        int row = m0 + wm + mf * 16 + quad * 4 + r;
        if (row < N_NODES) {
          float vv = acc[mf][nf][r] + bv;
          if constexpr (RELU) vv = fmaxf(vv, 0.f);
          if constexpr (std::is_same_v<TC, float>)
            C[(long)row * NOUT + col] = vv;
          else
            C[(long)row * NOUT + col] = (bf16)vv;
        }
      }
    }
}

// ---------------------------------------------------------------------------
extern "C" void kernel_launch(void* const* d_in, const int* in_sizes, int n_in,
                              void* d_out, int out_size, void* d_ws, size_t ws_size,
                              hipStream_t stream) {
  const float* x    = (const float*)d_in[0];
  const int*   esrc = (const int*)d_in[1];
  const int*   edst = (const int*)d_in[2];
  const float* evl  = (const float*)d_in[3];
  const float* eps  = (const float*)d_in[4];
  const float* w1   = (const float*)d_in[5];
  const float* b1   = (const float*)d_in[6];
  const float* w2   = (const float*)d_in[7];
  const float* b2   = (const float*)d_in[8];
  float* out = (float*)d_out;

  // workspace layout (16B aligned)
  bf16* agg = (bf16*)d_ws;                        // 12.8 MB
  bf16* xb  = agg + (size_t)N_NODES * D_IN;       // 12.8 MB
  bf16* h   = xb + (size_t)N_NODES * D_IN;        // 25.6 MB
  bf16* w1t = h + (size_t)N_NODES * D_HID;        // 64 KB
  bf16* w2t = w1t + D_IN * D_HID;                 // 64 KB

  prep_kernel<<<(N_NODES * D_IN / 4) / 256, 256, 0, stream>>>(
      x, w1, w2, xb, w1t, w2t);
  edge_csr_kernel<<<(N_NODES / NPW + 3) / 4, 256, 0, stream>>>(
      xb, esrc, edst, evl, eps, agg);
  gemm<D_IN, D_HID, true, bf16>
      <<<dim3((N_NODES + 63) / 64, D_HID / 64), 256, 0, stream>>>(agg, w1t, b1, h);
  gemm<D_HID, D_OUT, false, float>
      <<<dim3((N_NODES + 63) / 64, D_OUT / 64), 256, 0, stream>>>(h, w2t, b2, out);
}

// Round 9
// 157.832 us; speedup vs baseline: 2.4716x; 1.3446x over previous
//
#include <hip/hip_runtime.h>
#include <hip/hip_bf16.h>
#include <cstdint>
#include <type_traits>

#define N_NODES 50000
#define N_EDGES 800000
#define D_IN 128
#define D_HID 256
#define D_OUT 128

typedef __bf16 bf16;
typedef __bf16 bf16x8 __attribute__((ext_vector_type(8)));
typedef __bf16 bf16x4 __attribute__((ext_vector_type(4)));
typedef float f32x4 __attribute__((ext_vector_type(4)));

// ---------------------------------------------------------------------------
// Kernel 1 (R4-proven): aggb = bf16((1+eps)*x), xb = bf16(x), transposed
// bf16 weights. grid: 6250 x 256 = N*D_IN/4 exactly.
// ---------------------------------------------------------------------------
__global__ __launch_bounds__(256) void prep_kernel(
    const float* __restrict__ x, const float* __restrict__ eps,
    const float* __restrict__ w1, const float* __restrict__ w2,
    bf16* __restrict__ aggb, bf16* __restrict__ xb,
    bf16* __restrict__ w1t, bf16* __restrict__ w2t) {
  const int i = blockIdx.x * 256 + threadIdx.x;
  const float scale = 1.0f + eps[0];
  float4 v = ((const float4*)x)[i];
  ((bf16x4*)xb)[i] = bf16x4{(bf16)v.x, (bf16)v.y, (bf16)v.z, (bf16)v.w};
  ((bf16x4*)aggb)[i] = bf16x4{(bf16)(v.x * scale), (bf16)(v.y * scale),
                              (bf16)(v.z * scale), (bf16)(v.w * scale)};
  if (i < D_IN * D_HID) {            // 32768
    int k = i >> 8, n = i & 255;     // w1[k][n]
    w1t[n * D_IN + k] = (bf16)w1[i];
  } else if (i < 2 * D_IN * D_HID) { // next 32768
    int j = i - D_IN * D_HID;
    int k = j >> 7, n = j & 127;     // w2[k][n]
    w2t[n * D_HID + k] = (bf16)w2[j];
  }
}

// ---------------------------------------------------------------------------
// Kernel 2: R4's edge-centric kernel (measured <=43 us; LDS=0, conflicts=0 —
// unlike all CSR variants, it has NO dynamically-indexed local arrays) with
// two additions:
//  (a) sched_barrier(0) pins all 16 gathers before the serial consume.
//  (b) interior-run plain stores: a run that STARTS inside this 64-edge
//      chunk (cur != dst[e0]) also ends inside it -> its node is touched by
//      no other wave -> flush = plain store of self+acc (self prefetched
//      from prep-initialized aggb at run start). Only the first run and the
//      final flush (which may span chunk boundaries) remain atomic.
//      Tests the TCC-atomic-throughput hypothesis: ~4M -> ~1.6M atomics.
// grid: 3125 x 256 (4 waves/block) = 12500 waves; 64 edges/wave exactly.
// ---------------------------------------------------------------------------
__device__ __forceinline__ void flush_atomic(bf16* __restrict__ agg, int node,
                                             int lane, float2 acc) {
  union { struct { bf16 x, y; } h; int i; } u;
  u.h.x = (bf16)acc.x; u.h.y = (bf16)acc.y;
  const bf16* p = &agg[(long)node * D_IN + lane * 2];
  asm volatile("global_atomic_pk_add_bf16 %0, %1, off"
               :: "v"(p), "v"(u.i) : "memory");
}

__device__ __forceinline__ void flush_store(bf16* __restrict__ agg, int node,
                                            int lane, float2 a) {
  union { struct { bf16 x, y; } h; int i; } u;
  u.h.x = (bf16)a.x; u.h.y = (bf16)a.y;
  *(int*)&agg[(long)node * D_IN + lane * 2] = u.i;
}

__global__ __launch_bounds__(256) void edge_agg_kernel(
    const bf16* __restrict__ xb, const int* __restrict__ src,
    const int* __restrict__ dst, const float* __restrict__ val,
    bf16* __restrict__ agg) {
  const int wave = (blockIdx.x << 2) | (threadIdx.x >> 6);
  const int lane = threadIdx.x & 63;
  const int e0 = __builtin_amdgcn_readfirstlane(wave << 6);

  float2 acc = make_float2(0.f, 0.f);
  const int d0 = dst[e0];            // first dst of this chunk
  int cur = d0;
  float2 selfrow = make_float2(0.f, 0.f);  // valid only for interior runs

  #pragma unroll 1
  for (int j = 0; j < 64; j += 16) {
    int s[16], d[16];
    float v[16];
    #pragma unroll
    for (int t = 0; t < 16; ++t) {   // uniform addresses -> scalar loads
      s[t] = src[e0 + j + t];
      d[t] = dst[e0 + j + t];
      v[t] = val[e0 + j + t];
    }
    int g[16];  // packed bf16x2 gathers — 16 independent loads in flight
    #pragma unroll
    for (int t = 0; t < 16; ++t)
      g[t] = *(const int*)&xb[(long)s[t] * D_IN + lane * 2];
    __builtin_amdgcn_sched_barrier(0);  // pin: all gathers issued before use
    #pragma unroll
    for (int t = 0; t < 16; ++t) {
      if (d[t] != cur) {             // run boundary (wave-uniform at runtime)
        if (cur == d0) {
          flush_atomic(agg, cur, lane, acc);   // first run: may be shared
        } else {
          // interior run: exclusively owned -> overwrite self+acc
          flush_store(agg, cur, lane,
                      make_float2(selfrow.x + acc.x, selfrow.y + acc.y));
        }
        acc.x = 0.f; acc.y = 0.f;
        cur = d[t];
        // prefetch this node's self-term (prep wrote aggb = (1+eps)x);
        // consumed at the run's flush, ~a run-length of edges later.
        int p = *(const int*)&agg[(long)cur * D_IN + lane * 2];
        selfrow.x = __uint_as_float((unsigned)p << 16);
        selfrow.y = __uint_as_float((unsigned)p & 0xffff0000u);
      }
      float gx = __uint_as_float((unsigned)g[t] << 16);
      float gy = __uint_as_float((unsigned)g[t] & 0xffff0000u);
      acc.x = fmaf(v[t], gx, acc.x);
      acc.y = fmaf(v[t], gy, acc.y);
    }
  }
  flush_atomic(agg, cur, lane, acc);  // final run: may span into next chunk
}

// ---------------------------------------------------------------------------
// Kernels 3/4 (verbatim R4): C[M,NOUT] = act(A[M,KDIM] @ Wt[NOUT,KDIM]^T + b).
// LDS-staged 64x64 tiles, stride 136. Fragment layouts verified rounds 1-8:
//   A: a[j]=A[l15][quad*8+j]; B: b[j]=Wt[l15][quad*8+j]; C: row=quad*4+r, col=l15.
// ---------------------------------------------------------------------------
template <int KDIM, int NOUT, bool RELU, typename TC>
__global__ __launch_bounds__(256) void gemm(
    const bf16* __restrict__ A, const bf16* __restrict__ Wt,
    const float* __restrict__ bias, TC* __restrict__ C) {
  constexpr int LDL = 136;
  __shared__ alignas(16) bf16 As[64][LDL];
  __shared__ alignas(16) bf16 Bs[64][LDL];
  const int tid = threadIdx.x;
  const int m0 = blockIdx.x * 64;
  const int n0 = blockIdx.y * 64;
  const int wave = tid >> 6;
  const int lane = tid & 63;
  const int wm = (wave >> 1) * 32;
  const int wn = (wave & 1) * 32;
  const int l15 = lane & 15;
  const int quad = lane >> 4;
  f32x4 acc[2][2] = {};
  for (int kt = 0; kt < KDIM; kt += 128) {
    #pragma unroll
    for (int it = 0; it < 4; ++it) {
      int idx = tid + it * 256;
      int r = idx >> 4, c8 = (idx & 15) << 3;
      int row = m0 + r; if (row >= N_NODES) row = N_NODES - 1;
      *(bf16x8*)&As[r][c8] = *(const bf16x8*)&A[(long)row * KDIM + kt + c8];
    }
    #pragma unroll
    for (int it = 0; it < 4; ++it) {
      int idx = tid + it * 256;
      int r = idx >> 4, c8 = (idx & 15) << 3;
      *(bf16x8*)&Bs[r][c8] = *(const bf16x8*)&Wt[(long)(n0 + r) * KDIM + kt + c8];
    }
    __syncthreads();
    #pragma unroll
    for (int ks = 0; ks < 4; ++ks) {
      int kq = ks * 32 + quad * 8;
      bf16x8 a0 = *(const bf16x8*)&As[wm + l15][kq];
      bf16x8 a1 = *(const bf16x8*)&As[wm + 16 + l15][kq];
      bf16x8 b0 = *(const bf16x8*)&Bs[wn + l15][kq];
      bf16x8 b1 = *(const bf16x8*)&Bs[wn + 16 + l15][kq];
      acc[0][0] = __builtin_amdgcn_mfma_f32_16x16x32_bf16(a0, b0, acc[0][0], 0, 0, 0);
      acc[0][1] = __builtin_amdgcn_mfma_f32_16x16x32_bf16(a0, b1, acc[0][1], 0, 0, 0);
      acc[1][0] = __builtin_amdgcn_mfma_f32_16x16x32_bf16(a1, b0, acc[1][0], 0, 0, 0);
      acc[1][1] = __builtin_amdgcn_mfma_f32_16x16x32_bf16(a1, b1, acc[1][1], 0, 0, 0);
    }
    __syncthreads();
  }
  #pragma unroll
  for (int mf = 0; mf < 2; ++mf)
    #pragma unroll
    for (int nf = 0; nf < 2; ++nf) {
      int col = n0 + wn + nf * 16 + l15;
      float bv = bias[col];
      #pragma unroll
      for (int r = 0; r < 4; ++r) {
        int row = m0 + wm + mf * 16 + quad * 4 + r;
        if (row < N_NODES) {
          float vv = acc[mf][nf][r] + bv;
          if constexpr (RELU) vv = fmaxf(vv, 0.f);
          if constexpr (std::is_same_v<TC, float>)
            C[(long)row * NOUT + col] = vv;
          else
            C[(long)row * NOUT + col] = (bf16)vv;
        }
      }
    }
}

// ---------------------------------------------------------------------------
extern "C" void kernel_launch(void* const* d_in, const int* in_sizes, int n_in,
                              void* d_out, int out_size, void* d_ws, size_t ws_size,
                              hipStream_t stream) {
  const float* x    = (const float*)d_in[0];
  const int*   esrc = (const int*)d_in[1];
  const int*   edst = (const int*)d_in[2];
  const float* evl  = (const float*)d_in[3];
  const float* eps  = (const float*)d_in[4];
  const float* w1   = (const float*)d_in[5];
  const float* b1   = (const float*)d_in[6];
  const float* w2   = (const float*)d_in[7];
  const float* b2   = (const float*)d_in[8];
  float* out = (float*)d_out;

  // workspace layout (16B aligned)
  bf16* aggb = (bf16*)d_ws;                       // 12.8 MB
  bf16* xb   = aggb + (size_t)N_NODES * D_IN;     // 12.8 MB
  bf16* h    = xb + (size_t)N_NODES * D_IN;       // 25.6 MB
  bf16* w1t  = h + (size_t)N_NODES * D_HID;       // 64 KB
  bf16* w2t  = w1t + D_IN * D_HID;                // 64 KB

  prep_kernel<<<(N_NODES * D_IN / 4) / 256, 256, 0, stream>>>(
      x, eps, w1, w2, aggb, xb, w1t, w2t);
  edge_agg_kernel<<<N_EDGES / 256, 256, 0, stream>>>(xb, esrc, edst, evl, aggb);
  gemm<D_IN, D_HID, true, bf16>
      <<<dim3((N_NODES + 63) / 64, D_HID / 64), 256, 0, stream>>>(aggb, w1t, b1, h);
  gemm<D_HID, D_OUT, false, float>
      <<<dim3((N_NODES + 63) / 64, D_OUT / 64), 256, 0, stream>>>(h, w2t, b2, out);
}